// Round 5
// baseline (684.895 us; speedup 1.0000x reference)
//
#include <hip/hip_runtime.h>
#include <hip/hip_bf16.h>

#define B_ 32
#define PS_ 1536
#define TNS_ 2048
#define NJ_ 128
#define QK_ 384
#define NC_ 200
#define BN_EPS_ 1e-5f

typedef __attribute__((ext_vector_type(8))) short short8;
typedef __attribute__((ext_vector_type(4))) float float4v;
typedef unsigned short ushort_t;

__device__ __forceinline__ unsigned short f2b(float f) {
    unsigned int u = __float_as_uint(f);
    return (unsigned short)((u + 0x7FFFu + ((u >> 16) & 1u)) >> 16);
}
__device__ __forceinline__ float b2f_lo(unsigned int u) { return __uint_as_float(u << 16); }
__device__ __forceinline__ float b2f_hi(unsigned int u) { return __uint_as_float(u & 0xffff0000u); }

// ------------- MFMA tile machinery: 64(M)x128(N) block, BK=64, 4 waves ------
// wave grid 1M x 4N: each wave owns 64(M) x 32(N); acc[4][2]
// LDS rows padded 64->72 shorts (2-way bank conflict = free, m136)
__device__ __forceinline__ void mma_chunk42(const short* As, const short* Bs,
                                            int wn, int lane, float4v acc[4][2]) {
    const int m0 = lane & 15;
    const int n0 = wn + (lane & 15);
    const int quad = lane >> 4;
    #pragma unroll
    for (int kk = 0; kk < 64; kk += 32) {
        short8 a[4], b[2];
        const int kb = quad * 8 + kk;
        #pragma unroll
        for (int i = 0; i < 4; ++i) a[i] = *(const short8*)&As[(m0 + i * 16) * 72 + kb];
        #pragma unroll
        for (int j = 0; j < 2; ++j) b[j] = *(const short8*)&Bs[(n0 + j * 16) * 72 + kb];
        #pragma unroll
        for (int i = 0; i < 4; ++i)
            #pragma unroll
            for (int j = 0; j < 2; ++j)
                acc[i][j] = __builtin_amdgcn_mfma_f32_16x16x32_bf16(a[i], b[j], acc[i][j], 0, 0, 0);
    }
}

// stage 64 rows x 64 cols fp32 -> bf16 LDS (256 threads)
__device__ __forceinline__ void stage_f32_64r(const float* __restrict__ src, size_t stride,
                                              short* dst, int tid) {
    #pragma unroll
    for (int p = 0; p < 4; ++p) {
        int r = (tid >> 4) + p * 16;
        int kq = (tid & 15) * 4;
        float4 v = *(const float4*)(src + (size_t)r * stride + kq);
        ushort4 u = { f2b(v.x), f2b(v.y), f2b(v.z), f2b(v.w) };
        *(ushort4*)&dst[r * 72 + kq] = u;
    }
}
// stage 128 rows x 64 cols bf16 -> LDS (256 threads)
__device__ __forceinline__ void stage_b16_128r(const ushort_t* __restrict__ src, size_t stride,
                                               short* dst, int tid) {
    #pragma unroll
    for (int p = 0; p < 4; ++p) {
        int r = (tid >> 3) + p * 32;
        int kq = (tid & 7) * 8;
        uint4 v = *(const uint4*)(src + (size_t)r * stride + kq);
        *(uint4*)&dst[r * 72 + kq] = v;
    }
}
// stage 64 rows x 64 cols bf16 -> LDS (256 threads)
__device__ __forceinline__ void stage_b16_64r(const ushort_t* __restrict__ src, size_t stride,
                                              short* dst, int tid) {
    #pragma unroll
    for (int p = 0; p < 2; ++p) {
        int r = (tid >> 3) + p * 32;
        int kq = (tid & 7) * 8;
        uint4 v = *(const uint4*)(src + (size_t)r * stride + kq);
        *(uint4*)&dst[r * 72 + kq] = v;
    }
}

// ---------------- prep: column-means, scalar reductions, bf16 converts, zeroing
__global__ void k_prep_all(const float* __restrict__ wq, const float* __restrict__ bq,
                           const float* __restrict__ wk, const float* __restrict__ bk,
                           const float* __restrict__ wp1,
                           const float* __restrict__ w0, const float* __restrict__ wc1,
                           float* __restrict__ wqb, float* __restrict__ wkb,
                           float* __restrict__ scal,
                           float* __restrict__ bnsum, float* __restrict__ bnsq,
                           float* __restrict__ q1, float* __restrict__ k1,
                           ushort_t* __restrict__ w0b, ushort_t* __restrict__ wc1b) {
    const int blk = blockIdx.x;
    const int tid = threadIdx.x;
    if (blk < 6) {
        int c = blk * 256 + tid;
        float s = 0.f;
        for (int o = 0; o < QK_; ++o) s += wq[(size_t)o * PS_ + c];
        wqb[c] = s * (1.0f / QK_);
        bnsum[c] = 0.f; bnsq[c] = 0.f;          // zero BN accumulators for atomics
    } else if (blk < 12) {
        int c = (blk - 6) * 256 + tid;
        float s = 0.f;
        for (int o = 0; o < QK_; ++o) s += wk[(size_t)o * PS_ + c];
        wkb[c] = s * (1.0f / QK_);
    } else if (blk == 12) {
        __shared__ float red[256];
        float s = (tid < QK_ ? bq[tid] : 0.f) + (tid + 256 < QK_ ? bq[tid + 256] : 0.f);
        red[tid] = s; __syncthreads();
        for (int off = 128; off > 0; off >>= 1) { if (tid < off) red[tid] += red[tid + off]; __syncthreads(); }
        if (tid == 0) scal[0] = red[0] * (1.0f / QK_);
        __syncthreads();
        s = (tid < QK_ ? bk[tid] : 0.f) + (tid + 256 < QK_ ? bk[tid + 256] : 0.f);
        red[tid] = s; __syncthreads();
        for (int off = 128; off > 0; off >>= 1) { if (tid < off) red[tid] += red[tid + off]; __syncthreads(); }
        if (tid == 0) scal[1] = red[0] * (1.0f / QK_);
        __syncthreads();
        s = (tid < NJ_ ? wp1[tid] : 0.f);
        red[tid] = s; __syncthreads();
        for (int off = 128; off > 0; off >>= 1) { if (tid < off) red[tid] += red[tid + off]; __syncthreads(); }
        if (tid == 0) scal[2] = red[0];
    } else if (blk < 269) {
        int i = (blk - 13) * 256 + tid;          // 65536 float4s of w_pool0
        float4 v = ((const float4*)w0)[i];
        ushort4 u = { f2b(v.x), f2b(v.y), f2b(v.z), f2b(v.w) };
        ((ushort4*)w0b)[i] = u;
    } else if (blk < 2573) {
        int i = (blk - 269) * 256 + tid;         // 589824 float4s of w_c1
        float4 v = ((const float4*)wc1)[i];
        ushort4 u = { f2b(v.x), f2b(v.y), f2b(v.z), f2b(v.w) };
        ((ushort4*)wc1b)[i] = u;
    } else {
        int i = (blk - 2573) * 256 + tid;        // zero q1 (4096) then k1 (4096)
        if (i < 4096) q1[i] = 0.f; else k1[i - 4096] = 0.f;
    }
}

// ---------------- GEMM1 + fused q1/k1 partials ------------------------------
// M-tile 64: 768 blocks x 256 threads = exactly 3 blocks/CU (balanced)
// hsT[b][j][c] = sum_s x[(b,c),s]*w0[j,s] + b0[j]  (bf16)
// q1[b][j] += sum_c wqb[c]*round(hsT)   (atomic, on rounded values)
__global__ __launch_bounds__(256) void k_gemm1(const float* __restrict__ x,
        const ushort_t* __restrict__ w0b, const float* __restrict__ b0,
        const float* __restrict__ wqb, const float* __restrict__ wkb,
        ushort_t* __restrict__ hsT, float* __restrict__ q1, float* __restrict__ k1) {
    __shared__ __align__(16) short smem[64 * 72 + 128 * 72];
    short* As = smem;
    short* Bs = smem + 64 * 72;
    const int tid = threadIdx.x, lane = tid & 63, wave = tid >> 6;
    const int wn = wave * 32;
    const size_t m0r = (size_t)blockIdx.x * 64;      // row = b*PS + cb
    float4v acc[4][2] = {};
    for (int k0 = 0; k0 < TNS_; k0 += 64) {
        stage_f32_64r(x + m0r * TNS_ + k0, TNS_, As, tid);
        stage_b16_128r(w0b + k0, TNS_, Bs, tid);
        __syncthreads();
        mma_chunk42(As, Bs, wn, lane, acc);
        __syncthreads();
    }
    const int b = blockIdx.x / 24, cb = (blockIdx.x % 24) * 64;
    const int quad = lane >> 4, s = lane & 15;
    float sq[2] = { 0.f, 0.f }, sk[2] = { 0.f, 0.f };
    #pragma unroll
    for (int jn = 0; jn < 2; ++jn) {
        int j = wn + jn * 16 + s;
        float bj = b0[j];
        #pragma unroll
        for (int im = 0; im < 4; ++im) {
            int c = cb + im * 16 + quad * 4;
            float4v v = acc[im][jn];
            unsigned short us[4];
            #pragma unroll
            for (int r = 0; r < 4; ++r) {
                us[r] = f2b(v[r] + bj);
                float vr = b2f_lo((unsigned int)us[r]);
                sq[jn] += wqb[c + r] * vr;
                sk[jn] += wkb[c + r] * vr;
            }
            ushort4 u = { us[0], us[1], us[2], us[3] };
            *(ushort4*)&hsT[((size_t)(b * NJ_ + j)) * PS_ + c] = u;
        }
    }
    #pragma unroll
    for (int jn = 0; jn < 2; ++jn) {
        sq[jn] += __shfl_xor(sq[jn], 16, 64); sq[jn] += __shfl_xor(sq[jn], 32, 64);
        sk[jn] += __shfl_xor(sk[jn], 16, 64); sk[jn] += __shfl_xor(sk[jn], 32, 64);
    }
    if (quad == 0) {
        #pragma unroll
        for (int jn = 0; jn < 2; ++jn) {
            int j = wn + jn * 16 + s;
            atomicAdd(&q1[b * NJ_ + j], sq[jn]);
            atomicAdd(&k1[b * NJ_ + j], sk[jn]);
        }
    }
}

// ---------------- A1t[b][j2][j] = adj[j][j2] + tanh(q1[j]-k1[j2])*alpha ----
__global__ void k_a1(const float* __restrict__ adj, const float* __restrict__ q1,
                     const float* __restrict__ k1, const float* __restrict__ alpha,
                     const float* __restrict__ scal, ushort_t* __restrict__ A1t) {
    int idx = blockIdx.x * 256 + threadIdx.x;   // b*16384 + j2*128 + j
    int b = idx >> 14;
    int r = idx & 16383;
    int j2 = r >> 7;
    int j = r & 127;
    float dbias = scal[0] - scal[1];
    float t = tanhf(q1[b * NJ_ + j] - k1[b * NJ_ + j2] + dbias);
    A1t[idx] = f2b(adj[j * NJ_ + j2] + t * alpha[0]);
}

// ---- fused GEMM2+GEMM3+BN-stats+pool-dot (no hs3 materialization):
// M-tile 64: 768 blocks x 256 threads, XCD-chunked swizzle so same-b blocks
// share one XCD's L2 copy of hsT[b].
//   C1[o][j]   = sum_c wc1[o][c]*hsT[b][j][c] + bc1[o]   (bf16, LDS overlay)
//   hs3[c][j2] = sum_j C1[c][j]*A1t[b][j2][j]            (register only, bf16-rounded)
//   bnsum/bnsq += per-c sums of rounded hs3; d[b][c] = sum_j2 wp1[j2]*rounded hs3
__global__ __launch_bounds__(256) void k_gemm23(const ushort_t* __restrict__ wc1b,
        const float* __restrict__ bc1, const ushort_t* __restrict__ hsT,
        const ushort_t* __restrict__ A1t, const float* __restrict__ wp1,
        float* __restrict__ bnsum, float* __restrict__ bnsq, float* __restrict__ dout) {
    // single contiguous LDS block: As (64x72) | Bs (128x72); C1 overlay (64x136
    // = 8704 shorts) provably fits inside the 13824-short combined region.
    __shared__ __align__(16) short smem[64 * 72 + 128 * 72];
    __shared__ float bns_s[64], bnq_s[64], ds_s[64];
    short* As = smem;
    short* Bs = smem + 64 * 72;
    const int tid = threadIdx.x, lane = tid & 63, wave = tid >> 6;
    const int wn = wave * 32;
    // bijective XCD-chunk swizzle (768 % 8 == 0): XCD k gets b in [4k, 4k+4)
    const int bid = blockIdx.x;
    const int swz = (bid & 7) * 96 + (bid >> 3);
    const int bx = swz % 24, b = swz / 24;
    const int ob = bx * 64;
    if (tid < 64) { bns_s[tid] = 0.f; bnq_s[tid] = 0.f; ds_s[tid] = 0.f; }
    float4v acc[4][2] = {};
    const ushort_t* Abase = wc1b + (size_t)ob * PS_;
    const ushort_t* Bbase = hsT + (size_t)b * NJ_ * PS_;
    for (int k0 = 0; k0 < PS_; k0 += 64) {
        stage_b16_64r(Abase + k0, PS_, As, tid);
        stage_b16_128r(Bbase + k0, PS_, Bs, tid);
        __syncthreads();
        mma_chunk42(As, Bs, wn, lane, acc);
        __syncthreads();
    }
    // ---- write C1 (+bias, bf16) into LDS overlay [o][136] (64*136 shorts)
    short* C1 = smem;
    const int quad = lane >> 4, s = lane & 15;
    #pragma unroll
    for (int im = 0; im < 4; ++im) {
        int o0l = im * 16 + quad * 4;           // local o (0..63)
        float bc[4] = { bc1[ob + o0l], bc1[ob + o0l + 1], bc1[ob + o0l + 2], bc1[ob + o0l + 3] };
        #pragma unroll
        for (int jn = 0; jn < 2; ++jn) {
            int j = wn + jn * 16 + s;
            float4v v = acc[im][jn];
            #pragma unroll
            for (int r = 0; r < 4; ++r)
                C1[(o0l + r) * 136 + j] = (short)f2b(v[r] + bc[r]);
        }
    }
    __syncthreads();
    // ---- phase 2: acc2[c][j2] = sum_j C1[c][j]*A1t[j2][j], K = 128
    float4v acc2[4][2] = {};
    const ushort_t* Ap = A1t + (size_t)b * NJ_ * NJ_;
    const int m0 = s, n0 = wn + s;
    #pragma unroll
    for (int kk = 0; kk < 128; kk += 32) {
        short8 a[4], bf[2];
        const int kb = quad * 8 + kk;
        #pragma unroll
        for (int i = 0; i < 4; ++i) a[i] = *(const short8*)&C1[(m0 + i * 16) * 136 + kb];
        #pragma unroll
        for (int j = 0; j < 2; ++j) bf[j] = *(const short8*)&Ap[(size_t)(n0 + j * 16) * NJ_ + kb];
        #pragma unroll
        for (int i = 0; i < 4; ++i)
            #pragma unroll
            for (int j = 0; j < 2; ++j)
                acc2[i][j] = __builtin_amdgcn_mfma_f32_16x16x32_bf16(a[i], bf[j], acc2[i][j], 0, 0, 0);
    }
    // ---- epilogue: BN stats + pool-dot on rounded values (per-im to limit VGPR)
    #pragma unroll
    for (int im = 0; im < 4; ++im) {
        float s4[4] = {}, q4[4] = {}, d4[4] = {};
        #pragma unroll
        for (int jn = 0; jn < 2; ++jn) {
            int j2 = wn + jn * 16 + s;
            float w1 = wp1[j2];
            float4v v = acc2[im][jn];
            #pragma unroll
            for (int r = 0; r < 4; ++r) {
                float vr = b2f_lo((unsigned int)f2b(v[r]));
                s4[r] += vr; q4[r] += vr * vr; d4[r] += w1 * vr;
            }
        }
        #pragma unroll
        for (int m = 1; m < 16; m <<= 1)
            #pragma unroll
            for (int r = 0; r < 4; ++r) {
                s4[r] += __shfl_xor(s4[r], m, 64);
                q4[r] += __shfl_xor(q4[r], m, 64);
                d4[r] += __shfl_xor(d4[r], m, 64);
            }
        if (s == 0) {
            #pragma unroll
            for (int r = 0; r < 4; ++r) {
                int cl = im * 16 + quad * 4 + r;
                atomicAdd(&bns_s[cl], s4[r]);
                atomicAdd(&bnq_s[cl], q4[r]);
                atomicAdd(&ds_s[cl], d4[r]);
            }
        }
    }
    __syncthreads();
    if (tid < 64) {
        atomicAdd(&bnsum[ob + tid], bns_s[tid]);
        atomicAdd(&bnsq[ob + tid], bnq_s[tid]);
        dout[(size_t)b * PS_ + ob + tid] = ds_s[tid];
    }
}

// ---------------- classifier with inline BN fold ---------------------------
__global__ void k_cls(const float* __restrict__ dout, const float* __restrict__ bnsum,
                      const float* __restrict__ bnsq, const float* __restrict__ gamma,
                      const float* __restrict__ beta, const float* __restrict__ scal,
                      const float* __restrict__ bp1, const float* __restrict__ wcls,
                      const float* __restrict__ bcls, float* __restrict__ out) {
    int gid = blockIdx.x * 256 + threadIdx.x;
    int w = gid >> 6;              // 0..6399
    int lane = gid & 63;
    int b = w / 200, n = w % 200;
    const float* dp = dout + (size_t)b * PS_;
    const float* wp = wcls + (size_t)n * PS_;
    float sc2 = scal[2], bb = bp1[0];
    float acc = 0.f;
    for (int c = lane; c < PS_; c += 64) {
        float mean = bnsum[c] * (1.0f / 4096.0f);
        float var = bnsq[c] * (1.0f / 4096.0f) - mean * mean;
        float sc = gamma[c] * rsqrtf(var + BN_EPS_);
        float pval = sc * dp[c] + (beta[c] - sc * mean) * sc2 + bb;
        acc += wp[c] * pval;
    }
    #pragma unroll
    for (int off = 32; off > 0; off >>= 1) acc += __shfl_down(acc, off, 64);
    if (lane == 0) out[w] = acc + bcls[n];
}

extern "C" void kernel_launch(void* const* d_in, const int* in_sizes, int n_in,
                              void* d_out, int out_size, void* d_ws, size_t ws_size,
                              hipStream_t stream) {
    const float* x       = (const float*)d_in[0];
    const float* w_pool0 = (const float*)d_in[1];
    const float* b_pool0 = (const float*)d_in[2];
    const float* adj1    = (const float*)d_in[3];
    const float* w_q     = (const float*)d_in[4];
    const float* b_q     = (const float*)d_in[5];
    const float* w_k     = (const float*)d_in[6];
    const float* b_k     = (const float*)d_in[7];
    const float* alpha   = (const float*)d_in[8];
    const float* w_c1    = (const float*)d_in[9];
    const float* b_c1    = (const float*)d_in[10];
    const float* gamma   = (const float*)d_in[11];
    const float* beta    = (const float*)d_in[12];
    const float* w_pool1 = (const float*)d_in[13];
    const float* b_pool1 = (const float*)d_in[14];
    const float* w_cls   = (const float*)d_in[15];
    const float* b_cls   = (const float*)d_in[16];
    float* out = (float*)d_out;

    // workspace layout (hs2/hs3b regions retained but unused; offsets unchanged)
    ushort_t* hsT  = (ushort_t*)d_ws;          // 6,291,456 bf16 (B*NJ x PS)
    ushort_t* hs2  = hsT + 6291456;            // (unused)
    ushort_t* hs3b = hs2 + 6291456;            // (unused)
    ushort_t* w0b  = hs3b + 6291456;           // 262,144 bf16
    ushort_t* wc1b = w0b + 262144;             // 2,359,296 bf16
    ushort_t* A1t  = wc1b + 2359296;           // 524,288 bf16
    float* fb    = (float*)(A1t + 524288);     // 44,040,192 B so far (16B aligned)
    float* wqb   = fb;                         // 1536
    float* wkb   = wqb + 1536;                 // 1536
    float* scal  = wkb + 1536;                 // 16
    float* q1    = scal + 16;                  // 4096
    float* k1    = q1 + 4096;                  // 4096
    float* bnsum = k1 + 4096;                  // 1536
    float* bnsq  = bnsum + 1536;               // 1536
    float* dbuf  = bnsq + 1536;                // 49152 (pool-dot d[b][c])
    size_t need = 44040192u + (size_t)(1536 + 1536 + 16 + 4096 + 4096 + 1536 + 1536 + 49152) * 4;
    if (ws_size < need) return;

    k_prep_all<<<2605, 256, 0, stream>>>(w_q, b_q, w_k, b_k, w_pool1, w_pool0, w_c1,
                                         wqb, wkb, scal, bnsum, bnsq, q1, k1, w0b, wc1b);
    k_gemm1 <<<768, 256, 0, stream>>>(x, w0b, b_pool0, wqb, wkb, hsT, q1, k1);
    k_a1    <<<2048, 256, 0, stream>>>(adj1, q1, k1, alpha, scal, A1t);
    k_gemm23<<<768, 256, 0, stream>>>(wc1b, b_c1, hsT, A1t, w_pool1,
                                      bnsum, bnsq, dbuf);
    k_cls   <<<1600, 256, 0, stream>>>(dbuf, bnsum, bnsq, gamma, beta, scal,
                                       b_pool1, w_cls, b_cls, out);
}

// Round 6
// 667.527 us; speedup vs baseline: 1.0260x; 1.0260x over previous
//
#include <hip/hip_runtime.h>
#include <hip/hip_bf16.h>

#define B_ 32
#define PS_ 1536
#define TNS_ 2048
#define NJ_ 128
#define QK_ 384
#define NC_ 200
#define BN_EPS_ 1e-5f

typedef __attribute__((ext_vector_type(8))) short short8;
typedef __attribute__((ext_vector_type(4))) float float4v;
typedef unsigned short ushort_t;

__device__ __forceinline__ unsigned short f2b(float f) {
    unsigned int u = __float_as_uint(f);
    return (unsigned short)((u + 0x7FFFu + ((u >> 16) & 1u)) >> 16);
}
__device__ __forceinline__ float b2f_lo(unsigned int u) { return __uint_as_float(u << 16); }
__device__ __forceinline__ float b2f_hi(unsigned int u) { return __uint_as_float(u & 0xffff0000u); }

// ---------------- 512-thread staging helpers (128x128 tile, BK=64) ---------
// LDS rows padded 64->72 shorts (2-way bank conflict = free)
__device__ __forceinline__ void stage_f32_512(const float* __restrict__ src, size_t stride,
                                              short* dst, int tid) {
    #pragma unroll
    for (int p = 0; p < 4; ++p) {
        int r = (tid >> 4) + p * 32;
        int kq = (tid & 15) * 4;
        float4 v = *(const float4*)(src + (size_t)r * stride + kq);
        ushort4 u = { f2b(v.x), f2b(v.y), f2b(v.z), f2b(v.w) };
        *(ushort4*)&dst[r * 72 + kq] = u;
    }
}
__device__ __forceinline__ void stage_b16_512(const ushort_t* __restrict__ src, size_t stride,
                                              short* dst, int tid) {
    #pragma unroll
    for (int p = 0; p < 2; ++p) {
        int r = (tid >> 3) + p * 64;
        int kq = (tid & 7) * 8;
        uint4 v = *(const uint4*)(src + (size_t)r * stride + kq);
        *(uint4*)&dst[r * 72 + kq] = v;
    }
}
// stage 96 rows x 64 cols bf16 -> LDS (512 threads, 3x 8B per thread)
__device__ __forceinline__ void stage_b16_96r(const ushort_t* __restrict__ src, size_t stride,
                                              short* dst, int tid) {
    #pragma unroll
    for (int p = 0; p < 3; ++p) {
        int r = (tid >> 4) + p * 32;
        int kq = (tid & 15) * 4;
        ushort4 v = *(const ushort4*)(src + (size_t)r * stride + kq);
        *(ushort4*)&dst[r * 72 + kq] = v;
    }
}

// mma over 64(M per-wave slice via wm)x32(N) with acc[4][2] (128-row A tile)
__device__ __forceinline__ void mma_128(const short* As, const short* Bs,
                                        int wm, int wn, int lane, float4v acc[4][2]) {
    const int m0 = wm + (lane & 15);
    const int n0 = wn + (lane & 15);
    const int quad = lane >> 4;
    #pragma unroll
    for (int kk = 0; kk < 64; kk += 32) {
        short8 a[4], b[2];
        const int kb = quad * 8 + kk;
        #pragma unroll
        for (int i = 0; i < 4; ++i) a[i] = *(const short8*)&As[(m0 + i * 16) * 72 + kb];
        #pragma unroll
        for (int j = 0; j < 2; ++j) b[j] = *(const short8*)&Bs[(n0 + j * 16) * 72 + kb];
        #pragma unroll
        for (int i = 0; i < 4; ++i)
            #pragma unroll
            for (int j = 0; j < 2; ++j)
                acc[i][j] = __builtin_amdgcn_mfma_f32_16x16x32_bf16(a[i], b[j], acc[i][j], 0, 0, 0);
    }
}
// mma over 48(M per-wave slice)x32(N) with acc[3][2] (96-row A tile)
__device__ __forceinline__ void mma_96(const short* As, const short* Bs,
                                       int wm, int wn, int lane, float4v acc[3][2]) {
    const int m0 = wm + (lane & 15);
    const int n0 = wn + (lane & 15);
    const int quad = lane >> 4;
    #pragma unroll
    for (int kk = 0; kk < 64; kk += 32) {
        short8 a[3], b[2];
        const int kb = quad * 8 + kk;
        #pragma unroll
        for (int i = 0; i < 3; ++i) a[i] = *(const short8*)&As[(m0 + i * 16) * 72 + kb];
        #pragma unroll
        for (int j = 0; j < 2; ++j) b[j] = *(const short8*)&Bs[(n0 + j * 16) * 72 + kb];
        #pragma unroll
        for (int i = 0; i < 3; ++i)
            #pragma unroll
            for (int j = 0; j < 2; ++j)
                acc[i][j] = __builtin_amdgcn_mfma_f32_16x16x32_bf16(a[i], b[j], acc[i][j], 0, 0, 0);
    }
}

// ---------------- prep: column-means, scalar reductions, bf16 converts, zeroing
__global__ void k_prep_all(const float* __restrict__ wq, const float* __restrict__ bq,
                           const float* __restrict__ wk, const float* __restrict__ bk,
                           const float* __restrict__ wp1,
                           const float* __restrict__ w0, const float* __restrict__ wc1,
                           float* __restrict__ wqb, float* __restrict__ wkb,
                           float* __restrict__ scal,
                           float* __restrict__ bnsum, float* __restrict__ bnsq,
                           float* __restrict__ q1, float* __restrict__ k1,
                           ushort_t* __restrict__ w0b, ushort_t* __restrict__ wc1b) {
    const int blk = blockIdx.x;
    const int tid = threadIdx.x;
    if (blk < 6) {
        int c = blk * 256 + tid;
        float s = 0.f;
        for (int o = 0; o < QK_; ++o) s += wq[(size_t)o * PS_ + c];
        wqb[c] = s * (1.0f / QK_);
        bnsum[c] = 0.f; bnsq[c] = 0.f;          // zero BN accumulators for atomics
    } else if (blk < 12) {
        int c = (blk - 6) * 256 + tid;
        float s = 0.f;
        for (int o = 0; o < QK_; ++o) s += wk[(size_t)o * PS_ + c];
        wkb[c] = s * (1.0f / QK_);
    } else if (blk == 12) {
        __shared__ float red[256];
        float s = (tid < QK_ ? bq[tid] : 0.f) + (tid + 256 < QK_ ? bq[tid + 256] : 0.f);
        red[tid] = s; __syncthreads();
        for (int off = 128; off > 0; off >>= 1) { if (tid < off) red[tid] += red[tid + off]; __syncthreads(); }
        if (tid == 0) scal[0] = red[0] * (1.0f / QK_);
        __syncthreads();
        s = (tid < QK_ ? bk[tid] : 0.f) + (tid + 256 < QK_ ? bk[tid + 256] : 0.f);
        red[tid] = s; __syncthreads();
        for (int off = 128; off > 0; off >>= 1) { if (tid < off) red[tid] += red[tid + off]; __syncthreads(); }
        if (tid == 0) scal[1] = red[0] * (1.0f / QK_);
        __syncthreads();
        s = (tid < NJ_ ? wp1[tid] : 0.f);
        red[tid] = s; __syncthreads();
        for (int off = 128; off > 0; off >>= 1) { if (tid < off) red[tid] += red[tid + off]; __syncthreads(); }
        if (tid == 0) scal[2] = red[0];
    } else if (blk < 269) {
        int i = (blk - 13) * 256 + tid;          // 65536 float4s of w_pool0
        float4 v = ((const float4*)w0)[i];
        ushort4 u = { f2b(v.x), f2b(v.y), f2b(v.z), f2b(v.w) };
        ((ushort4*)w0b)[i] = u;
    } else if (blk < 2573) {
        int i = (blk - 269) * 256 + tid;         // 589824 float4s of w_c1
        float4 v = ((const float4*)wc1)[i];
        ushort4 u = { f2b(v.x), f2b(v.y), f2b(v.z), f2b(v.w) };
        ((ushort4*)wc1b)[i] = u;
    } else {
        int i = (blk - 2573) * 256 + tid;        // zero q1 (4096) then k1 (4096)
        if (i < 4096) q1[i] = 0.f; else k1[i - 4096] = 0.f;
    }
}

// ---------------- GEMM1 + fused q1/k1 partials (R3-proven geometry) ---------
// 384 blocks x 512 thr, 128x128 tile; HBM-BW-bound on the 402 MB x read
__global__ __launch_bounds__(512) void k_gemm1(const float* __restrict__ x,
        const ushort_t* __restrict__ w0b, const float* __restrict__ b0,
        const float* __restrict__ wqb, const float* __restrict__ wkb,
        ushort_t* __restrict__ hsT, float* __restrict__ q1, float* __restrict__ k1) {
    __shared__ __align__(16) short As[128 * 72];
    __shared__ __align__(16) short Bs[128 * 72];
    const int tid = threadIdx.x, lane = tid & 63, wave = tid >> 6;
    const int wm = (wave >> 2) * 64, wn = (wave & 3) * 32;
    const size_t m0r = (size_t)blockIdx.x * 128;
    float4v acc[4][2] = {};
    for (int k0 = 0; k0 < TNS_; k0 += 64) {
        stage_f32_512(x + m0r * TNS_ + k0, TNS_, As, tid);
        stage_b16_512(w0b + k0, TNS_, Bs, tid);
        __syncthreads();
        mma_128(As, Bs, wm, wn, lane, acc);
        __syncthreads();
    }
    const int b = blockIdx.x / 12, cb = (blockIdx.x % 12) * 128;
    const int quad = lane >> 4, s = lane & 15;
    float sq[2] = { 0.f, 0.f }, sk[2] = { 0.f, 0.f };
    #pragma unroll
    for (int jn = 0; jn < 2; ++jn) {
        int j = wn + jn * 16 + s;
        float bj = b0[j];
        #pragma unroll
        for (int im = 0; im < 4; ++im) {
            int c = cb + wm + im * 16 + quad * 4;
            float4v v = acc[im][jn];
            unsigned short us[4];
            #pragma unroll
            for (int r = 0; r < 4; ++r) {
                us[r] = f2b(v[r] + bj);
                float vr = b2f_lo((unsigned int)us[r]);
                sq[jn] += wqb[c + r] * vr;
                sk[jn] += wkb[c + r] * vr;
            }
            ushort4 u = { us[0], us[1], us[2], us[3] };
            *(ushort4*)&hsT[((size_t)(b * NJ_ + j)) * PS_ + c] = u;
        }
    }
    #pragma unroll
    for (int jn = 0; jn < 2; ++jn) {
        sq[jn] += __shfl_xor(sq[jn], 16, 64); sq[jn] += __shfl_xor(sq[jn], 32, 64);
        sk[jn] += __shfl_xor(sk[jn], 16, 64); sk[jn] += __shfl_xor(sk[jn], 32, 64);
    }
    if (quad == 0) {
        #pragma unroll
        for (int jn = 0; jn < 2; ++jn) {
            int j = wn + jn * 16 + s;
            atomicAdd(&q1[b * NJ_ + j], sq[jn]);
            atomicAdd(&k1[b * NJ_ + j], sk[jn]);
        }
    }
}

// ---------------- A1t[b][j2][j] = adj[j][j2] + tanh(q1[j]-k1[j2])*alpha ----
__global__ void k_a1(const float* __restrict__ adj, const float* __restrict__ q1,
                     const float* __restrict__ k1, const float* __restrict__ alpha,
                     const float* __restrict__ scal, ushort_t* __restrict__ A1t) {
    int idx = blockIdx.x * 256 + threadIdx.x;   // b*16384 + j2*128 + j
    int b = idx >> 14;
    int r = idx & 16383;
    int j2 = r >> 7;
    int j = r & 127;
    float dbias = scal[0] - scal[1];
    float t = tanhf(q1[b * NJ_ + j] - k1[b * NJ_ + j2] + dbias);
    A1t[idx] = f2b(adj[j * NJ_ + j2] + t * alpha[0]);
}

// ---- fused GEMM2+GEMM3+BN-stats+pool-dot, balanced 2 blocks/CU ------------
// 96-row o-tiles: 16 ob-tiles x 32 b = 512 blocks x 512 thr = 2/CU exactly.
// XCD-chunk swizzle (512%8==0): XCD k gets b in [4k,4k+4) -> hsT[b] L2-local.
//   C1[o][j]   = sum_c wc1[o][c]*hsT[b][j][c] + bc1[o]   (bf16, LDS overlay)
//   hs3[c][j2] = sum_j C1[c][j]*A1t[b][j2][j]            (register only, rounded)
//   bnsum/bnsq += per-c sums; d[b][c] = sum_j2 wp1[j2]*rounded hs3
__global__ __launch_bounds__(512) void k_gemm23(const ushort_t* __restrict__ wc1b,
        const float* __restrict__ bc1, const ushort_t* __restrict__ hsT,
        const ushort_t* __restrict__ A1t, const float* __restrict__ wp1,
        float* __restrict__ bnsum, float* __restrict__ bnsq, float* __restrict__ dout) {
    // contiguous LDS: As (96x72) | Bs (128x72) = 16128 shorts; C1 overlay
    // (96x136 = 13056 shorts) provably fits.
    __shared__ __align__(16) short smem[96 * 72 + 128 * 72];
    __shared__ float bns_s[96], bnq_s[96], ds_s[96];
    short* As = smem;
    short* Bs = smem + 96 * 72;
    const int tid = threadIdx.x, lane = tid & 63, wave = tid >> 6;
    const int wm = (wave >> 2) * 48, wn = (wave & 3) * 32;
    // bijective XCD-chunk swizzle
    const int bid = blockIdx.x;
    const int swz = (bid & 7) * 64 + (bid >> 3);
    const int b = swz >> 4, ob = (swz & 15) * 96;
    if (tid < 96) { bns_s[tid] = 0.f; bnq_s[tid] = 0.f; ds_s[tid] = 0.f; }
    float4v acc[3][2] = {};
    const ushort_t* Abase = wc1b + (size_t)ob * PS_;
    const ushort_t* Bbase = hsT + (size_t)b * NJ_ * PS_;
    for (int k0 = 0; k0 < PS_; k0 += 64) {
        stage_b16_96r(Abase + k0, PS_, As, tid);
        stage_b16_512(Bbase + k0, PS_, Bs, tid);
        __syncthreads();
        mma_96(As, Bs, wm, wn, lane, acc);
        __syncthreads();
    }
    // ---- write C1 (+bias, bf16) into LDS overlay [o][136]
    short* C1 = smem;
    const int quad = lane >> 4, s = lane & 15;
    #pragma unroll
    for (int im = 0; im < 3; ++im) {
        int o0l = wm + im * 16 + quad * 4;      // local o (0..95)
        float bc[4] = { bc1[ob + o0l], bc1[ob + o0l + 1], bc1[ob + o0l + 2], bc1[ob + o0l + 3] };
        #pragma unroll
        for (int jn = 0; jn < 2; ++jn) {
            int j = wn + jn * 16 + s;
            float4v v = acc[im][jn];
            #pragma unroll
            for (int r = 0; r < 4; ++r)
                C1[(o0l + r) * 136 + j] = (short)f2b(v[r] + bc[r]);
        }
    }
    __syncthreads();
    // ---- phase 2: acc2[c][j2] = sum_j C1[c][j]*A1t[j2][j], K = 128
    float4v acc2[3][2] = {};
    const ushort_t* Ap = A1t + (size_t)b * NJ_ * NJ_;
    const int m0 = wm + s, n0 = wn + s;
    #pragma unroll
    for (int kk = 0; kk < 128; kk += 32) {
        short8 a[3], bf[2];
        const int kb = quad * 8 + kk;
        #pragma unroll
        for (int i = 0; i < 3; ++i) a[i] = *(const short8*)&C1[(m0 + i * 16) * 136 + kb];
        #pragma unroll
        for (int j = 0; j < 2; ++j) bf[j] = *(const short8*)&Ap[(size_t)(n0 + j * 16) * NJ_ + kb];
        #pragma unroll
        for (int i = 0; i < 3; ++i)
            #pragma unroll
            for (int j = 0; j < 2; ++j)
                acc2[i][j] = __builtin_amdgcn_mfma_f32_16x16x32_bf16(a[i], bf[j], acc2[i][j], 0, 0, 0);
    }
    // ---- epilogue: BN stats + pool-dot on rounded values
    #pragma unroll
    for (int im = 0; im < 3; ++im) {
        float s4[4] = {}, q4[4] = {}, d4[4] = {};
        #pragma unroll
        for (int jn = 0; jn < 2; ++jn) {
            int j2 = wn + jn * 16 + s;
            float w1 = wp1[j2];
            float4v v = acc2[im][jn];
            #pragma unroll
            for (int r = 0; r < 4; ++r) {
                float vr = b2f_lo((unsigned int)f2b(v[r]));
                s4[r] += vr; q4[r] += vr * vr; d4[r] += w1 * vr;
            }
        }
        #pragma unroll
        for (int m = 1; m < 16; m <<= 1)
            #pragma unroll
            for (int r = 0; r < 4; ++r) {
                s4[r] += __shfl_xor(s4[r], m, 64);
                q4[r] += __shfl_xor(q4[r], m, 64);
                d4[r] += __shfl_xor(d4[r], m, 64);
            }
        if (s == 0) {
            #pragma unroll
            for (int r = 0; r < 4; ++r) {
                int cl = wm + im * 16 + quad * 4 + r;
                atomicAdd(&bns_s[cl], s4[r]);
                atomicAdd(&bnq_s[cl], q4[r]);
                atomicAdd(&ds_s[cl], d4[r]);
            }
        }
    }
    __syncthreads();
    if (tid < 96) {
        atomicAdd(&bnsum[ob + tid], bns_s[tid]);
        atomicAdd(&bnsq[ob + tid], bnq_s[tid]);
        dout[(size_t)b * PS_ + ob + tid] = ds_s[tid];
    }
}

// ---------------- classifier with inline BN fold ---------------------------
__global__ void k_cls(const float* __restrict__ dout, const float* __restrict__ bnsum,
                      const float* __restrict__ bnsq, const float* __restrict__ gamma,
                      const float* __restrict__ beta, const float* __restrict__ scal,
                      const float* __restrict__ bp1, const float* __restrict__ wcls,
                      const float* __restrict__ bcls, float* __restrict__ out) {
    int gid = blockIdx.x * 256 + threadIdx.x;
    int w = gid >> 6;              // 0..6399
    int lane = gid & 63;
    int b = w / 200, n = w % 200;
    const float* dp = dout + (size_t)b * PS_;
    const float* wp = wcls + (size_t)n * PS_;
    float sc2 = scal[2], bb = bp1[0];
    float acc = 0.f;
    for (int c = lane; c < PS_; c += 64) {
        float mean = bnsum[c] * (1.0f / 4096.0f);
        float var = bnsq[c] * (1.0f / 4096.0f) - mean * mean;
        float sc = gamma[c] * rsqrtf(var + BN_EPS_);
        float pval = sc * dp[c] + (beta[c] - sc * mean) * sc2 + bb;
        acc += wp[c] * pval;
    }
    #pragma unroll
    for (int off = 32; off > 0; off >>= 1) acc += __shfl_down(acc, off, 64);
    if (lane == 0) out[w] = acc + bcls[n];
}

extern "C" void kernel_launch(void* const* d_in, const int* in_sizes, int n_in,
                              void* d_out, int out_size, void* d_ws, size_t ws_size,
                              hipStream_t stream) {
    const float* x       = (const float*)d_in[0];
    const float* w_pool0 = (const float*)d_in[1];
    const float* b_pool0 = (const float*)d_in[2];
    const float* adj1    = (const float*)d_in[3];
    const float* w_q     = (const float*)d_in[4];
    const float* b_q     = (const float*)d_in[5];
    const float* w_k     = (const float*)d_in[6];
    const float* b_k     = (const float*)d_in[7];
    const float* alpha   = (const float*)d_in[8];
    const float* w_c1    = (const float*)d_in[9];
    const float* b_c1    = (const float*)d_in[10];
    const float* gamma   = (const float*)d_in[11];
    const float* beta    = (const float*)d_in[12];
    const float* w_pool1 = (const float*)d_in[13];
    const float* b_pool1 = (const float*)d_in[14];
    const float* w_cls   = (const float*)d_in[15];
    const float* b_cls   = (const float*)d_in[16];
    float* out = (float*)d_out;

    // workspace layout (hs2/hs3b regions retained but unused; offsets unchanged)
    ushort_t* hsT  = (ushort_t*)d_ws;          // 6,291,456 bf16 (B*NJ x PS)
    ushort_t* hs2  = hsT + 6291456;            // (unused)
    ushort_t* hs3b = hs2 + 6291456;            // (unused)
    ushort_t* w0b  = hs3b + 6291456;           // 262,144 bf16
    ushort_t* wc1b = w0b + 262144;             // 2,359,296 bf16
    ushort_t* A1t  = wc1b + 2359296;           // 524,288 bf16
    float* fb    = (float*)(A1t + 524288);     // 44,040,192 B so far (16B aligned)
    float* wqb   = fb;                         // 1536
    float* wkb   = wqb + 1536;                 // 1536
    float* scal  = wkb + 1536;                 // 16
    float* q1    = scal + 16;                  // 4096
    float* k1    = q1 + 4096;                  // 4096
    float* bnsum = k1 + 4096;                  // 1536
    float* bnsq  = bnsum + 1536;               // 1536
    float* dbuf  = bnsq + 1536;                // 49152 (pool-dot d[b][c])
    size_t need = 44040192u + (size_t)(1536 + 1536 + 16 + 4096 + 4096 + 1536 + 1536 + 49152) * 4;
    if (ws_size < need) return;

    k_prep_all<<<2605, 256, 0, stream>>>(w_q, b_q, w_k, b_k, w_pool1, w_pool0, w_c1,
                                         wqb, wkb, scal, bnsum, bnsq, q1, k1, w0b, wc1b);
    k_gemm1 <<<384, 512, 0, stream>>>(x, w0b, b_pool0, wqb, wkb, hsT, q1, k1);
    k_a1    <<<2048, 256, 0, stream>>>(adj1, q1, k1, alpha, scal, A1t);
    k_gemm23<<<512, 512, 0, stream>>>(wc1b, b_c1, hsT, A1t, w_pool1,
                                      bnsum, bnsq, dbuf);
    k_cls   <<<1600, 256, 0, stream>>>(dbuf, bnsum, bnsq, gamma, beta, scal,
                                       b_pool1, w_cls, b_cls, out);
}